// Round 7
// baseline (58.403 us; speedup 1.0000x reference)
//
#include <hip/hip_runtime.h>

#define N_WORD 32000
#define DIM    300
#define KP     320           // K padded to 10 x 32 for MFMA (A-side zero pad)
#define BQ     32
#define WW     8
#define NNEG   2392
#define PERB   (WW*NNEG)     // 19136
#define NTOT   (BQ*PERB)     // 612352
#define NBLK3  1024
#define FSCALE 268435456.0   // 2^28 fixed-point scale for deterministic atomic sum

typedef __attribute__((ext_vector_type(8))) short short8;   // 8 bf16 = 4 VGPR
typedef __attribute__((ext_vector_type(4))) float f32x4;

__device__ __forceinline__ unsigned f2b2(float lo, float hi) {
  // pack two floats to two RNE-rounded bf16 in one u32
  unsigned ul = __builtin_bit_cast(unsigned, lo);
  unsigned uh = __builtin_bit_cast(unsigned, hi);
  ul = (ul + 0x7FFF + ((ul >> 16) & 1)) >> 16;
  uh = (uh + 0x7FFF + ((uh >> 16) & 1));
  return (ul & 0xFFFFu) | (uh & 0xFFFF0000u);
}
__device__ __forceinline__ unsigned short f2b(float f) {
  unsigned u = __builtin_bit_cast(unsigned, f);
  return (unsigned short)((u + 0x7FFF + ((u >> 16) & 1)) >> 16);
}

// ---- kernel 1: tgt bags -> bf16-packed [32][320] (zero k-pad); zero atomics ----
__global__ __launch_bounds__(256) void prep_kernel(
    const float* __restrict__ char_emb, const float* __restrict__ compo_emb,
    const int* __restrict__ chars, const int* __restrict__ compos,
    unsigned short* __restrict__ tgt_bf,
    unsigned long long* __restrict__ acc, int* __restrict__ cnt) {
  if (blockIdx.x == 0 && threadIdx.x == 0) { *acc = 0ULL; *cnt = 0; }
  int b = blockIdx.x;
  for (int d = threadIdx.x; d < KP; d += 256) {
    float a = 0.f;
    if (d < DIM) {
      #pragma unroll
      for (int j = 0; j < 4; ++j) {
        int c = chars[b*4 + j];
        if (c != 1) a += char_emb[(size_t)c*DIM + d];
      }
      #pragma unroll
      for (int j = 0; j < 8; ++j) {
        int c = compos[b*8 + j];
        if (c != 1) a += compo_emb[(size_t)c*DIM + d];
      }
    }
    tgt_bf[b*KP + d] = (d < DIM) ? f2b(a) : (unsigned short)0;
  }
}

// ---- kernel 2: streaming MFMA GEMM, no LDS, no barrier ----
// Each wave owns 16 word rows (v = blk*64 + wv*16 + ln); B-fragments loaded
// directly from word_emb as per-lane float4 pairs (16 rows x 128 B per k-step,
// every line consumed), converted f32->bf16 in regs. A-fragments from the
// 20 KB L1/L2-hot tgt_bf. All loads independent -> memory pipe never drains.
__global__ __launch_bounds__(256, 2) void s_gemm_kernel(
    const float* __restrict__ w, const unsigned short* __restrict__ tgt_bf,
    float* __restrict__ S) {
  int tid = threadIdx.x, wv = tid >> 6, lane = tid & 63;
  int ln = lane & 15, g = lane >> 4;
  int v = blockIdx.x*64 + wv*16 + ln;
  const float* rp = w + (size_t)v*DIM;
  const unsigned short* ar0 = tgt_bf + ln*KP;
  const unsigned short* ar1 = tgt_bf + (16 + ln)*KP;

  f32x4 acc0 = {0.f,0.f,0.f,0.f}, acc1 = {0.f,0.f,0.f,0.f};
  #pragma unroll
  for (int kb = 0; kb < 9; ++kb) {
    const float* p = rp + kb*32 + g*8;
    float4 f0 = *(const float4*)p;
    float4 f1 = *(const float4*)(p + 4);
    short8 bf;
    unsigned* bu = (unsigned*)&bf;
    bu[0] = f2b2(f0.x, f0.y); bu[1] = f2b2(f0.z, f0.w);
    bu[2] = f2b2(f1.x, f1.y); bu[3] = f2b2(f1.z, f1.w);
    short8 a0 = *(const short8*)(ar0 + kb*32 + g*8);
    short8 a1 = *(const short8*)(ar1 + kb*32 + g*8);
    acc0 = __builtin_amdgcn_mfma_f32_16x16x32_bf16(a0, bf, acc0, 0, 0, 0);
    acc1 = __builtin_amdgcn_mfma_f32_16x16x32_bf16(a1, bf, acc1, 0, 0, 0);
  }
  {  // tail k-step: k in [288,320); valid dims < 300, A is zero-padded there
    int k0 = 288 + g*8;
    float4 f0 = {0.f,0.f,0.f,0.f}, f1 = {0.f,0.f,0.f,0.f};
    if (k0 < 300)     f0 = *(const float4*)(rp + k0);       // g=0,1
    if (k0 + 4 < 300) f1 = *(const float4*)(rp + k0 + 4);   // g=0 only
    short8 bf;
    unsigned* bu = (unsigned*)&bf;
    bu[0] = f2b2(f0.x, f0.y); bu[1] = f2b2(f0.z, f0.w);
    bu[2] = f2b2(f1.x, f1.y); bu[3] = f2b2(f1.z, f1.w);
    short8 a0 = *(const short8*)(ar0 + 288 + g*8);
    short8 a1 = *(const short8*)(ar1 + 288 + g*8);
    acc0 = __builtin_amdgcn_mfma_f32_16x16x32_bf16(a0, bf, acc0, 0, 0, 0);
    acc1 = __builtin_amdgcn_mfma_f32_16x16x32_bf16(a1, bf, acc1, 0, 0, 0);
  }

  // D: col = lane&15 (v), row = (lane>>4)*4 + reg (b)  [m89-verified]
  #pragma unroll
  for (int r = 0; r < 4; ++r) {
    int b0 = g*4 + r;
    S[(size_t)b0*N_WORD + v]        = acc0[r];
    S[(size_t)(b0 + 16)*N_WORD + v] = acc1[r];
  }
}

// ---- kernel 3: gather S at noise/ctx indices, sum log-sigmoid; fused final ----
// Deterministic cross-block sum: per-block float partial -> fixed-point int64
// atomicAdd (integer adds are order-invariant); last block writes the output.
__global__ __launch_bounds__(256) void loss_kernel(
    const float* __restrict__ S, const int* __restrict__ noise,
    const int* __restrict__ ctx, unsigned long long* __restrict__ acc,
    int* __restrict__ cnt, float* __restrict__ out) {
  float a = 0.f;
  for (int i = blockIdx.x*256 + threadIdx.x; i < NTOT; i += 256*NBLK3) {
    int b = i / PERB;                 // constant divisor -> magic mul
    int idx = noise[i];
    float s = S[(size_t)b*N_WORD + idx];
    a += __logf(1.f/(1.f + __expf(s)) + 1e-32f);
  }
  if (blockIdx.x == 0) {
    int i = threadIdx.x;              // i = b*8 + w covers all 256 (b,w)
    int c = ctx[i];
    float s = (c == 1) ? 0.f : S[(size_t)(i >> 3)*N_WORD + c];
    a += __logf(1.f/(1.f + __expf(-s)));
  }
  #pragma unroll
  for (int off = 32; off > 0; off >>= 1) a += __shfl_down(a, off);
  __shared__ float wsum[4];
  int lane = threadIdx.x & 63, wid = threadIdx.x >> 6;
  if (lane == 0) wsum[wid] = a;
  __syncthreads();
  if (threadIdx.x == 0) {
    float partial = wsum[0] + wsum[1] + wsum[2] + wsum[3];
    unsigned long long enc =
        (unsigned long long)(long long)llrintf(partial * (float)FSCALE);
    atomicAdd(acc, enc);
    __threadfence();
    int old = atomicAdd(cnt, 1);
    if (old == NBLK3 - 1) {           // last block: all adds visible
      long long tot = (long long)atomicAdd(acc, 0ULL);
      out[0] = (float)(-((double)tot / FSCALE) / (double)BQ);
    }
  }
}

extern "C" void kernel_launch(void* const* d_in, const int* in_sizes, int n_in,
                              void* d_out, int out_size, void* d_ws, size_t ws_size,
                              hipStream_t stream) {
  const float* word_emb  = (const float*)d_in[0];   // [32000,300]
  const float* char_emb  = (const float*)d_in[1];   // [8000,300]
  const float* compo_emb = (const float*)d_in[2];   // [1000,300]
  const int*   chars     = (const int*)d_in[3];     // [32,4]
  const int*   compos    = (const int*)d_in[4];     // [32,8]
  const int*   ctx       = (const int*)d_in[5];     // [32,8]
  const int*   noise     = (const int*)d_in[6];     // [32,8,2392]
  float* out = (float*)d_out;

  char* ws = (char*)d_ws;
  unsigned short*     tgt_bf = (unsigned short*)(ws);            // 20480 B
  float*              S      = (float*)(ws + 20480);             // 4,096,000 B
  unsigned long long* acc    = (unsigned long long*)(ws + 20480 + 4096000);
  int*                cnt    = (int*)(ws + 20480 + 4096000 + 8);

  prep_kernel<<<BQ, 256, 0, stream>>>(char_emb, compo_emb, chars, compos,
                                      tgt_bf, acc, cnt);
  s_gemm_kernel<<<N_WORD/64, 256, 0, stream>>>(word_emb, tgt_bf, S);
  loss_kernel<<<NBLK3, 256, 0, stream>>>(S, noise, ctx, acc, cnt, out);
}